// Round 3
// baseline (6592.712 us; speedup 1.0000x reference)
//
#include <hip/hip_runtime.h>
#include <cstdint>
#include <cstddef>

// Problem constants (fixed by reference setup_inputs)
constexpr int Bb = 8;
constexpr int Nn = 8192;
constexpr int Ss = 2048;
constexpr int BS = Bb * Ss;  // 16384

// ---------------------------------------------------------------------------
// FPS: one block per batch, 256 threads (4 waves), 32 points/thread.
// Decision math is f64 (bit-matches the np reference — verified rounds 1,2).
// f32 screening: distf[] = (float)dist * 1.000002 is a certified upper bound,
// so skipping when d32 > distf only skips provable non-updates; f64 state
// stays bit-identical. 4 waves => cheap barrier, 4-entry final reduce done
// lane-parallel with 2 shuffle steps. Wave argmax (6 f64 shuffle steps) runs
// only when the wave's ballot reports a changed lane; cached otherwise.
// Single barrier per iteration via parity double-buffered rv/ri.
// ---------------------------------------------------------------------------
__global__ __launch_bounds__(256) void fps_kernel(const float* __restrict__ xyz,
                                                  float* __restrict__ new_xyz) {
  __shared__ float lx[Nn * 3];             // 96 KB: batch point cloud
  __shared__ double rv[2][4];
  __shared__ int ri[2][4];
  const int b = blockIdx.x;
  const int tid = threadIdx.x;
  const float* xb = xyz + (size_t)b * Nn * 3;
  for (int e = tid; e < Nn * 3; e += 256) lx[e] = xb[e];
  __syncthreads();
  float px[32], py[32], pz[32];
  double dist[32];
  float distf[32];
#pragma unroll
  for (int j = 0; j < 32; ++j) {
    const int p = tid + j * 256;
    px[j] = lx[p * 3 + 0];
    py[j] = lx[p * 3 + 1];
    pz[j] = lx[p * 3 + 2];
    dist[j] = 1e10;
    distf[j] = 3.0e38f;                    // force exact path on first touch
  }
  const int lane = tid & 63, wid = tid >> 6;
  int cur = 0;
  double lv = -1.0;                        // per-lane cached local argmax
  int li = tid;
  double wv_c = -1.0;                      // cached wave argmax (all lanes)
  int wi_c = 0;
  float* nxb = new_xyz + (size_t)b * Ss * 3;
  for (int i = 0; i < Ss; ++i) {
    const float cxf = lx[cur * 3 + 0], cyf = lx[cur * 3 + 1], czf = lx[cur * 3 + 2];
    if (tid == 0) { nxb[i * 3 + 0] = cxf; nxb[i * 3 + 1] = cyf; nxb[i * 3 + 2] = czf; }
    bool changed = false;
#pragma unroll
    for (int j = 0; j < 32; ++j) {
      const float dxf = px[j] - cxf;
      const float dyf = py[j] - cyf;
      const float dzf = pz[j] - czf;
      const float d32 = fmaf(dxf, dxf, fmaf(dyf, dyf, dzf * dzf));
      if (!(d32 > distf[j])) {             // possible update -> exact f64 path
        double dx = __dsub_rn((double)px[j], (double)cxf);
        double dy = __dsub_rn((double)py[j], (double)cyf);
        double dz = __dsub_rn((double)pz[j], (double)czf);
        double d = __dadd_rn(__dadd_rn(__dmul_rn(dx, dx), __dmul_rn(dy, dy)), __dmul_rn(dz, dz));
        if (d < dist[j]) {
          dist[j] = d;
          distf[j] = (float)d * 1.000002f;
          changed = true;
        }
      }
    }
    const unsigned long long anyb = __ballot(changed);
    if (changed) {                         // rescan local max only when needed
      lv = -1.0;
      li = 0;
#pragma unroll
      for (int j = 0; j < 32; ++j) {
        if (dist[j] > lv) { lv = dist[j]; li = tid + j * 256; }  // j asc => smallest idx on tie
      }
    }
    if (anyb) {                            // wave argmax only if wave changed
      double bv = lv;
      int bi = li;
#pragma unroll
      for (int off = 1; off < 64; off <<= 1) {
        double ov = __shfl_xor(bv, off);
        int oi = __shfl_xor(bi, off);
        if (ov > bv || (ov == bv && oi < bi)) { bv = ov; bi = oi; }
      }
      wv_c = bv;
      wi_c = bi;
    }
    const int pb = i & 1;
    if (lane == 0) { rv[pb][wid] = wv_c; ri[pb][wid] = wi_c; }
    __syncthreads();
    // all lanes: lane-parallel reduce of the 4 wave entries (2 shuffle steps)
    double gv = rv[pb][lane & 3];
    int gi = ri[pb][lane & 3];
#pragma unroll
    for (int off = 1; off < 4; off <<= 1) {
      double ov = __shfl_xor(gv, off);
      int oi = __shfl_xor(gi, off);
      if (ov > gv || (ov == gv && oi < gi)) { gv = ov; gi = oi; }
    }
    cur = gi;                              // identical in all lanes
  }
}

// ---------------------------------------------------------------------------
// Ball query, both scales fused. One wave per center. f64 distance compare
// (bit-matches np). First nsample in-range points in original order; pad with
// first hit (0 if none).
// ---------------------------------------------------------------------------
__global__ __launch_bounds__(256) void ballq_kernel(const float* __restrict__ xyz,
                                                    const float* __restrict__ nxyz,
                                                    int* __restrict__ idx0,
                                                    int* __restrict__ idx1) {
  const int wid = threadIdx.x >> 6, lane = threadIdx.x & 63;
  const int bs = blockIdx.x * 4 + wid;
  const int b = bs >> 11;  // S = 2048
  const float* xb = xyz + (size_t)b * Nn * 3;
  const double cx = (double)nxyz[bs * 3 + 0];
  const double cy = (double)nxyz[bs * 3 + 1];
  const double cz = (double)nxyz[bs * 3 + 2];
  const double R0 = 0.4 * 0.4, R1 = 0.8 * 0.8;
  int cnt0 = 0, cnt1 = 0, first0 = 0, first1 = 0;
  const unsigned long long lmask = (1ull << lane) - 1ull;
  for (int base = 0; base < Nn; base += 64) {
    const int p = base + lane;
    double dx = __dsub_rn((double)xb[p * 3 + 0], cx);
    double dy = __dsub_rn((double)xb[p * 3 + 1], cy);
    double dz = __dsub_rn((double)xb[p * 3 + 2], cz);
    double d2 = __dadd_rn(__dadd_rn(__dmul_rn(dx, dx), __dmul_rn(dy, dy)), __dmul_rn(dz, dz));
    const bool in0 = d2 < R0, in1 = d2 < R1;
    unsigned long long m0 = __ballot(in0);
    unsigned long long m1 = __ballot(in1);
    if (cnt0 < 16 && m0) {
      if (cnt0 == 0) first0 = base + __builtin_ctzll(m0);
      int r = (int)__popcll(m0 & lmask);
      if (in0 && cnt0 + r < 16) idx0[bs * 16 + cnt0 + r] = p;
      cnt0 += (int)__popcll(m0);
    }
    if (cnt1 < 32 && m1) {
      if (cnt1 == 0) first1 = base + __builtin_ctzll(m1);
      int r = (int)__popcll(m1 & lmask);
      if (in1 && cnt1 + r < 32) idx1[bs * 32 + cnt1 + r] = p;
      cnt1 += (int)__popcll(m1);
    }
    if (cnt0 >= 16 && cnt1 >= 32) break;
  }
  const int f0 = cnt0 < 16 ? cnt0 : 16;
  for (int j = f0 + lane; j < 16; j += 64) idx0[bs * 16 + j] = first0;
  const int f1 = cnt1 < 32 ? cnt1 : 32;
  for (int j = f1 + lane; j < 32; j += 64) idx1[bs * 32 + j] = first1;
}

// ---------------------------------------------------------------------------
// Generic tall-skinny GEMM with fused input transforms and BN-stat partials.
// Tile: 64 rows x COUT cols, 256 threads, per-thread 4 rows x (COUT/16) cols.
// MODE 0: gather (rel-xyz ++ features) via ball-query idx          (K=67)
// MODE 1: x = relu(bn(prev_raw)) from 64-ch buffer (in-place safe) (K=64)
// MODE 2: x = concat(relu(bn(pool0)), relu(bn(pool1)))             (K=256)
// MODE 3: x = plain read (already-normalized h)                    (K=256)
// POOL  : write per-group (NS) max of raw output instead of full rows.
// Every block writes per-channel (sum, sumsq) partials to P[ch][block].
// ---------------------------------------------------------------------------
template <int COUT, int KTOT, int MODE, int NS, bool POOL, bool BIAS>
__global__ __launch_bounds__(256) void mlp_gemm(
    const float* __restrict__ xin, const float* __restrict__ xin2,
    const float* __restrict__ bnp, const float* __restrict__ bnp2,
    const float* __restrict__ w, const float* __restrict__ bias,
    const int* __restrict__ gidx, const float* __restrict__ xyz,
    const float* __restrict__ nxyz, const float* __restrict__ feats,
    float* __restrict__ out, float* __restrict__ P) {
  constexpr int KC = (KTOT <= 68) ? KTOT : 32;     // K chunk
  constexpr int NCH = (KTOT + KC - 1) / KC;
  constexpr int TC = COUT / 16;                    // cols per thread
  constexpr int XPAD = KC + 1;
  constexpr int XSZ = 64 * XPAD;
  constexpr int EPI = (POOL ? 48 : 32) * COUT;
  constexpr int SM = (XSZ + KC * COUT > EPI) ? (XSZ + KC * COUT) : EPI;
  __shared__ float smem[SM];
  float* xS = smem;
  float* wS = smem + XSZ;

  const int tid = threadIdx.x;
  const int cg = tid & 15, rg = tid >> 4;
  const int row0 = blockIdx.x * 64;
  float acc[4][TC];
#pragma unroll
  for (int i = 0; i < 4; ++i)
#pragma unroll
    for (int t = 0; t < TC; ++t) acc[i][t] = 0.f;

  for (int ch = 0; ch < NCH; ++ch) {
    const int k0 = ch * KC;
    if (ch) __syncthreads();
    // ---- stage x tile [64 rows][KC] (row-major, padded) ----
    for (int e = tid; e < 64 * KC; e += 256) {
      const int r = e / KC, kk = e - r * KC;
      const int kg = k0 + kk;
      const int rowg = row0 + r;
      float v;
      if constexpr (MODE == 0) {
        const int bs = rowg / NS;
        const int p = gidx[rowg];
        const int bb = bs >> 11;
        if (kg < 3)
          v = xyz[(bb * Nn + p) * 3 + kg] - nxyz[bs * 3 + kg];
        else
          v = feats[((bb * Nn + p) << 6) + (kg - 3)];
      } else if constexpr (MODE == 1) {
        v = fmaxf((xin[(size_t)rowg * 64 + kg] - bnp[kg]) * bnp[64 + kg], 0.f);
      } else if constexpr (MODE == 2) {
        if (kg < 128)
          v = fmaxf((xin[(size_t)rowg * 128 + kg] - bnp[kg]) * bnp[128 + kg], 0.f);
        else {
          const int k2 = kg - 128;
          v = fmaxf((xin2[(size_t)rowg * 128 + k2] - bnp2[k2]) * bnp2[128 + k2], 0.f);
        }
      } else {
        v = xin[(size_t)rowg * 256 + kg];
      }
      xS[r * XPAD + kk] = v;
    }
    // ---- stage w chunk [KC][COUT] ----
    for (int e = tid; e < KC * COUT; e += 256) {
      const int kk = e / COUT, c = e - kk * COUT;
      wS[kk * COUT + c] = w[(size_t)(k0 + kk) * COUT + c];
    }
    __syncthreads();
    // ---- FMA loop ----
    for (int kk = 0; kk < KC; ++kk) {
      float xr[4];
#pragma unroll
      for (int i = 0; i < 4; ++i) xr[i] = xS[(rg * 4 + i) * XPAD + kk];
#pragma unroll
      for (int t = 0; t < TC; t += 4) {
        const float4 wv = *(const float4*)&wS[kk * COUT + cg * TC + t];
#pragma unroll
        for (int i = 0; i < 4; ++i) {
          acc[i][t + 0] = fmaf(xr[i], wv.x, acc[i][t + 0]);
          acc[i][t + 1] = fmaf(xr[i], wv.y, acc[i][t + 1]);
          acc[i][t + 2] = fmaf(xr[i], wv.z, acc[i][t + 2]);
          acc[i][t + 3] = fmaf(xr[i], wv.w, acc[i][t + 3]);
        }
      }
    }
  }
  __syncthreads();  // smem reuse below
  if constexpr (BIAS) {
#pragma unroll
    for (int t = 0; t < TC; ++t) {
      const float bv = bias[cg * TC + t];
#pragma unroll
      for (int i = 0; i < 4; ++i) acc[i][t] += bv;
    }
  }
  // ---- per-block BN partials (+ group max for POOL) ----
  float* ssum = smem;
  float* ssq = smem + 16 * COUT;
  float* pbuf = smem + 32 * COUT;
  const int colb = cg * TC;
#pragma unroll
  for (int t = 0; t < TC; ++t) {
    float s = 0.f, q = 0.f, m = -3.4e38f;
#pragma unroll
    for (int i = 0; i < 4; ++i) {
      const float v = acc[i][t];
      s += v;
      q = fmaf(v, v, q);
      m = fmaxf(m, v);
    }
    ssum[rg * COUT + colb + t] = s;
    ssq[rg * COUT + colb + t] = q;
    if constexpr (POOL) pbuf[rg * COUT + colb + t] = m;
  }
  __syncthreads();
  const int gX = gridDim.x;
  for (int c = tid; c < COUT; c += 256) {
    float s = 0.f, q = 0.f;
#pragma unroll
    for (int rr = 0; rr < 16; ++rr) {
      s += ssum[rr * COUT + c];
      q += ssq[rr * COUT + c];
    }
    P[(size_t)c * gX + blockIdx.x] = s;
    P[(size_t)(COUT + c) * gX + blockIdx.x] = q;
  }
  if constexpr (POOL) {
    constexpr int G = 64 / NS, RPG = NS / 4;
    for (int o = tid; o < G * COUT; o += 256) {
      const int g = o / COUT, c = o - g * COUT;
      float m = pbuf[(g * RPG) * COUT + c];
#pragma unroll
      for (int qq = 1; qq < RPG; ++qq) m = fmaxf(m, pbuf[(g * RPG + qq) * COUT + c]);
      out[(size_t)(blockIdx.x * G + g) * COUT + c] = m;
    }
  } else {
#pragma unroll
    for (int i = 0; i < 4; ++i) {
      float* op = out + (size_t)(row0 + rg * 4 + i) * COUT + colb;
#pragma unroll
      for (int t = 0; t < TC; t += 4) {
        *(float4*)(op + t) = make_float4(acc[i][t], acc[i][t + 1], acc[i][t + 2], acc[i][t + 3]);
      }
    }
  }
}

// ---------------------------------------------------------------------------
// BN finalize: one block per channel, coalesced partial reads, deterministic
// f64 LDS tree reduction -> mu, rstd. bnp layout: [mu(C), rstd(C)].
// ---------------------------------------------------------------------------
__global__ __launch_bounds__(256) void bn_finalize(const float* __restrict__ P, int gX,
                                                   int M, int C, float* __restrict__ bnp) {
  __shared__ double sh[512];
  const int c = blockIdx.x;
  const int tid = threadIdx.x;
  const float* psum = P + (size_t)c * gX;
  const float* psq = P + (size_t)(C + c) * gX;
  double s = 0, q = 0;
  for (int i = tid; i < gX; i += 256) {
    s += (double)psum[i];
    q += (double)psq[i];
  }
  sh[tid] = s;
  sh[256 + tid] = q;
  __syncthreads();
  for (int off = 128; off; off >>= 1) {
    if (tid < off) {
      sh[tid] += sh[tid + off];
      sh[256 + tid] += sh[256 + tid + off];
    }
    __syncthreads();
  }
  if (tid == 0) {
    const double invM = 1.0 / (double)M;
    const double mu = sh[0] * invM;
    const double var = sh[256] * invM - mu * mu;
    bnp[c] = (float)mu;
    bnp[C + c] = (float)(1.0 / sqrt(var + 1e-5));
  }
}

// h = relu(bn(agg_raw)) -> d_out (also consumed by conf layer)
__global__ __launch_bounds__(256) void h_store_kernel(const float* __restrict__ agg,
                                                      const float* __restrict__ bnp,
                                                      float* __restrict__ hout) {
  const int t = blockIdx.x * 256 + threadIdx.x;
  const int c = t & 255;
  const float v = (agg[t] - bnp[c]) * bnp[256 + c];
  hout[t] = fmaxf(v, 0.f);
}

// cls = relu(bn(conf_raw)) @ cls_w + cls_b   (one wave per row)
__global__ __launch_bounds__(256) void cls_kernel(const float* __restrict__ craw,
                                                  const float* __restrict__ bnp,
                                                  const float* __restrict__ clsw,
                                                  const float* __restrict__ clsb,
                                                  float* __restrict__ outc) {
  const int wid = threadIdx.x >> 6, lane = threadIdx.x & 63;
  const int row = blockIdx.x * 4 + wid;
  const float* cr = craw + (size_t)row * 256;
  float a0 = 0.f, a1 = 0.f, a2 = 0.f;
#pragma unroll 4
  for (int k = lane; k < 256; k += 64) {
    float x = fmaxf((cr[k] - bnp[k]) * bnp[256 + k], 0.f);
    a0 = fmaf(x, clsw[k * 3 + 0], a0);
    a1 = fmaf(x, clsw[k * 3 + 1], a1);
    a2 = fmaf(x, clsw[k * 3 + 2], a2);
  }
#pragma unroll
  for (int off = 32; off; off >>= 1) {
    a0 += __shfl_down(a0, off);
    a1 += __shfl_down(a1, off);
    a2 += __shfl_down(a2, off);
  }
  if (lane == 0) {
    outc[row * 3 + 0] = a0 + clsb[0];
    outc[row * 3 + 1] = a1 + clsb[1];
    outc[row * 3 + 2] = a2 + clsb[2];
  }
}

// ---------------------------------------------------------------------------
extern "C" void kernel_launch(void* const* d_in, const int* in_sizes, int n_in,
                              void* d_out, int out_size, void* d_ws, size_t ws_size,
                              hipStream_t stream) {
  (void)in_sizes; (void)n_in; (void)out_size; (void)ws_size;
  const float* xyz = (const float*)d_in[0];
  const float* feats = (const float*)d_in[1];
  const float* w00 = (const float*)d_in[2];
  const float* w01 = (const float*)d_in[3];
  const float* w02 = (const float*)d_in[4];
  const float* w10 = (const float*)d_in[5];
  const float* w11 = (const float*)d_in[6];
  const float* w12 = (const float*)d_in[7];
  const float* aggw = (const float*)d_in[8];
  const float* aggb = (const float*)d_in[9];
  const float* confw = (const float*)d_in[10];
  const float* clsw = (const float*)d_in[11];
  const float* clsb = (const float*)d_in[12];

  float* outp = (float*)d_out;
  float* nxyz = outp;                               // [BS,3]
  float* hout = outp + (size_t)BS * 3;              // [BS,256]
  float* clsout = hout + (size_t)BS * 256;          // [BS,3]

  char* ws = (char*)d_ws;
  const size_t MB = 1u << 20;
  int* idx0 = (int*)(ws + 0);                       // 1 MB
  int* idx1 = (int*)(ws + 1 * MB);                  // 2 MB
  float* bnb = (float*)(ws + 3 * MB);               // bn params (2048 floats)
  float* P = (float*)(ws + 4 * MB);                 // partials, up to 8 MB
  float* pool0 = (float*)(ws + 12 * MB);            // [BS,128]
  float* pool1 = (float*)(ws + 20 * MB);            // [BS,128]
  float* aggraw = (float*)(ws + 28 * MB);           // [BS,256]
  float* confraw = (float*)(ws + 44 * MB);          // [BS,256]
  float* hA = (float*)(ws + 60 * MB);               // [524288,64] (layers 1/2 in-place)

  fps_kernel<<<Bb, 256, 0, stream>>>(xyz, nxyz);
  ballq_kernel<<<BS / 4, 256, 0, stream>>>(xyz, nxyz, idx0, idx1);

  // ---- scale 0 (r=0.4, ns=16), M = 262144 ----
  mlp_gemm<64, 67, 0, 16, false, false><<<4096, 256, 0, stream>>>(
      nullptr, nullptr, nullptr, nullptr, w00, nullptr, idx0, xyz, nxyz, feats, hA, P);
  bn_finalize<<<64, 256, 0, stream>>>(P, 4096, 262144, 64, bnb + 0);
  mlp_gemm<64, 64, 1, 1, false, false><<<4096, 256, 0, stream>>>(
      hA, nullptr, bnb + 0, nullptr, w01, nullptr, nullptr, nullptr, nullptr, nullptr, hA, P);
  bn_finalize<<<64, 256, 0, stream>>>(P, 4096, 262144, 64, bnb + 128);
  mlp_gemm<128, 64, 1, 16, true, false><<<4096, 256, 0, stream>>>(
      hA, nullptr, bnb + 128, nullptr, w02, nullptr, nullptr, nullptr, nullptr, nullptr, pool0, P);
  bn_finalize<<<128, 256, 0, stream>>>(P, 4096, 262144, 128, bnb + 256);

  // ---- scale 1 (r=0.8, ns=32), M = 524288 ----
  mlp_gemm<64, 67, 0, 32, false, false><<<8192, 256, 0, stream>>>(
      nullptr, nullptr, nullptr, nullptr, w10, nullptr, idx1, xyz, nxyz, feats, hA, P);
  bn_finalize<<<64, 256, 0, stream>>>(P, 8192, 524288, 64, bnb + 512);
  mlp_gemm<64, 64, 1, 1, false, false><<<8192, 256, 0, stream>>>(
      hA, nullptr, bnb + 512, nullptr, w11, nullptr, nullptr, nullptr, nullptr, nullptr, hA, P);
  bn_finalize<<<64, 256, 0, stream>>>(P, 8192, 524288, 64, bnb + 640);
  mlp_gemm<128, 64, 1, 32, true, false><<<8192, 256, 0, stream>>>(
      hA, nullptr, bnb + 640, nullptr, w12, nullptr, nullptr, nullptr, nullptr, nullptr, pool1, P);
  bn_finalize<<<128, 256, 0, stream>>>(P, 8192, 524288, 128, bnb + 768);

  // ---- aggregation: concat(bn3_0(pool0), bn3_1(pool1)) @ agg_w + agg_b ----
  mlp_gemm<256, 256, 2, 1, false, true><<<256, 256, 0, stream>>>(
      pool0, pool1, bnb + 256, bnb + 768, aggw, aggb, nullptr, nullptr, nullptr, nullptr, aggraw, P);
  bn_finalize<<<256, 256, 0, stream>>>(P, 256, 16384, 256, bnb + 1024);
  h_store_kernel<<<BS, 256, 0, stream>>>(aggraw, bnb + 1024, hout);

  // ---- confidence hidden layer ----
  mlp_gemm<256, 256, 3, 1, false, false><<<256, 256, 0, stream>>>(
      hout, nullptr, nullptr, nullptr, confw, nullptr, nullptr, nullptr, nullptr, nullptr, confraw, P);
  bn_finalize<<<256, 256, 0, stream>>>(P, 256, 16384, 256, bnb + 1536);

  // ---- classifier ----
  cls_kernel<<<BS / 4, 256, 0, stream>>>(confraw, bnb + 1536, clsw, clsb, clsout);
}

// Round 4
// 4913.880 us; speedup vs baseline: 1.3417x; 1.3417x over previous
//
#include <hip/hip_runtime.h>
#include <cstdint>
#include <cstddef>

// Problem constants (fixed by reference setup_inputs)
constexpr int Bb = 8;
constexpr int Nn = 8192;
constexpr int Ss = 2048;
constexpr int BS = Bb * Ss;  // 16384

// ---------------------------------------------------------------------------
// FPS: one block per batch, 1024 threads, 8 points/thread (64 VGPR, no spill
// — the round-3 32-pts/thread variant spilled and regressed).
// Decision math is f64 (bit-matches the np reference — verified rounds 1-3).
// f32 screening with certified upper bound distf = (float)dist * 1.000002:
// skip only provable non-updates, f64 state stays bit-identical.
// Round-4 deltas: (1) no global store inside the loop (LDS index log, final
// gather) so __syncthreads no longer drains vmcnt; (2) lane-parallel 16-entry
// block reduce via 4-step xor shuffle; (3) branchless screening bitmask.
// ---------------------------------------------------------------------------
__global__ __launch_bounds__(1024) void fps_kernel(const float* __restrict__ xyz,
                                                   float* __restrict__ new_xyz) {
  __shared__ float lx[Nn * 3];             // 96 KB: batch point cloud
  __shared__ int sidx[Ss];                 // 8 KB: selected-index log
  __shared__ double rv[2][16];
  __shared__ int ri[2][16];
  const int b = blockIdx.x;
  const int tid = threadIdx.x;
  const float* xb = xyz + (size_t)b * Nn * 3;
  for (int e = tid; e < Nn * 3; e += 1024) lx[e] = xb[e];
  __syncthreads();
  float px[8], py[8], pz[8];
  double dist[8];
  float distf[8];
#pragma unroll
  for (int j = 0; j < 8; ++j) {
    const int p = tid + j * 1024;
    px[j] = lx[p * 3 + 0];
    py[j] = lx[p * 3 + 1];
    pz[j] = lx[p * 3 + 2];
    dist[j] = 1e10;
    distf[j] = 3.0e38f;                    // force exact path on first touch
  }
  const int lane = tid & 63, wid = tid >> 6;
  int cur = 0;
  double lv = -1.0;                        // per-lane cached local argmax
  int li = tid;
  double wv_c = -1.0;                      // cached wave argmax (all lanes)
  int wi_c = 0;
  for (int i = 0; i < Ss; ++i) {
    if (tid == 0) sidx[i] = cur;           // LDS log (visible after barrier)
    const float cxf = lx[cur * 3 + 0], cyf = lx[cur * 3 + 1], czf = lx[cur * 3 + 2];
    // ---- branchless f32 screening: which j might update? ----
    unsigned need = 0;
#pragma unroll
    for (int j = 0; j < 8; ++j) {
      const float dxf = px[j] - cxf;
      const float dyf = py[j] - cyf;
      const float dzf = pz[j] - czf;
      const float d32 = fmaf(dxf, dxf, fmaf(dyf, dyf, dzf * dzf));
      need |= (d32 <= distf[j]) ? (1u << j) : 0u;
    }
    bool changed = false;
    if (need) {                            // rare path: exact f64 updates
#pragma unroll
      for (int j = 0; j < 8; ++j) {
        if (need & (1u << j)) {
          double dx = __dsub_rn((double)px[j], (double)cxf);
          double dy = __dsub_rn((double)py[j], (double)cyf);
          double dz = __dsub_rn((double)pz[j], (double)czf);
          double d = __dadd_rn(__dadd_rn(__dmul_rn(dx, dx), __dmul_rn(dy, dy)),
                               __dmul_rn(dz, dz));
          if (d < dist[j]) {
            dist[j] = d;
            distf[j] = (float)d * 1.000002f;
            changed = true;
          }
        }
      }
    }
    const unsigned long long anyb = __ballot(changed);
    if (changed) {                         // rescan local max only when needed
      lv = -1.0;
      li = 0;
#pragma unroll
      for (int j = 0; j < 8; ++j) {
        if (dist[j] > lv) { lv = dist[j]; li = tid + j * 1024; }  // j asc => smallest idx on tie
      }
    }
    if (anyb) {                            // wave argmax only if wave changed
      double bv = lv;
      int bi = li;
#pragma unroll
      for (int off = 1; off < 64; off <<= 1) {
        double ov = __shfl_xor(bv, off);
        int oi = __shfl_xor(bi, off);
        if (ov > bv || (ov == bv && oi < bi)) { bv = ov; bi = oi; }
      }
      wv_c = bv;
      wi_c = bi;
    }
    const int pb = i & 1;
    if (lane == 0) { rv[pb][wid] = wv_c; ri[pb][wid] = wi_c; }
    __syncthreads();
    // lane-parallel reduce of the 16 wave entries (4 xor-shuffle steps)
    double gv = rv[pb][lane & 15];
    int gi = ri[pb][lane & 15];
#pragma unroll
    for (int off = 1; off < 16; off <<= 1) {
      double ov = __shfl_xor(gv, off);
      int oi = __shfl_xor(gi, off);
      if (ov > gv || (ov == gv && oi < gi)) { gv = ov; gi = oi; }
    }
    cur = gi;                              // identical in all lanes
  }
  __syncthreads();
  // final gather: new_xyz[i][c] = lx[sidx[i]*3 + c]
  float* nxb = new_xyz + (size_t)b * Ss * 3;
  for (int e = tid; e < Ss * 3; e += 1024) {
    const int i = e / 3, c = e - i * 3;
    nxb[e] = lx[sidx[i] * 3 + c];
  }
}

// ---------------------------------------------------------------------------
// Ball query, both scales fused. One wave per center. f64 distance compare
// (bit-matches np). First nsample in-range points in original order; pad with
// first hit (0 if none).
// ---------------------------------------------------------------------------
__global__ __launch_bounds__(256) void ballq_kernel(const float* __restrict__ xyz,
                                                    const float* __restrict__ nxyz,
                                                    int* __restrict__ idx0,
                                                    int* __restrict__ idx1) {
  const int wid = threadIdx.x >> 6, lane = threadIdx.x & 63;
  const int bs = blockIdx.x * 4 + wid;
  const int b = bs >> 11;  // S = 2048
  const float* xb = xyz + (size_t)b * Nn * 3;
  const double cx = (double)nxyz[bs * 3 + 0];
  const double cy = (double)nxyz[bs * 3 + 1];
  const double cz = (double)nxyz[bs * 3 + 2];
  const double R0 = 0.4 * 0.4, R1 = 0.8 * 0.8;
  int cnt0 = 0, cnt1 = 0, first0 = 0, first1 = 0;
  const unsigned long long lmask = (1ull << lane) - 1ull;
  for (int base = 0; base < Nn; base += 64) {
    const int p = base + lane;
    double dx = __dsub_rn((double)xb[p * 3 + 0], cx);
    double dy = __dsub_rn((double)xb[p * 3 + 1], cy);
    double dz = __dsub_rn((double)xb[p * 3 + 2], cz);
    double d2 = __dadd_rn(__dadd_rn(__dmul_rn(dx, dx), __dmul_rn(dy, dy)), __dmul_rn(dz, dz));
    const bool in0 = d2 < R0, in1 = d2 < R1;
    unsigned long long m0 = __ballot(in0);
    unsigned long long m1 = __ballot(in1);
    if (cnt0 < 16 && m0) {
      if (cnt0 == 0) first0 = base + __builtin_ctzll(m0);
      int r = (int)__popcll(m0 & lmask);
      if (in0 && cnt0 + r < 16) idx0[bs * 16 + cnt0 + r] = p;
      cnt0 += (int)__popcll(m0);
    }
    if (cnt1 < 32 && m1) {
      if (cnt1 == 0) first1 = base + __builtin_ctzll(m1);
      int r = (int)__popcll(m1 & lmask);
      if (in1 && cnt1 + r < 32) idx1[bs * 32 + cnt1 + r] = p;
      cnt1 += (int)__popcll(m1);
    }
    if (cnt0 >= 16 && cnt1 >= 32) break;
  }
  const int f0 = cnt0 < 16 ? cnt0 : 16;
  for (int j = f0 + lane; j < 16; j += 64) idx0[bs * 16 + j] = first0;
  const int f1 = cnt1 < 32 ? cnt1 : 32;
  for (int j = f1 + lane; j < 32; j += 64) idx1[bs * 32 + j] = first1;
}

// ---------------------------------------------------------------------------
// Generic tall-skinny GEMM with fused input transforms and BN-stat partials.
// Tile: 64 rows x COUT cols, 256 threads, per-thread 4 rows x (COUT/16) cols.
// MODE 0: gather (rel-xyz ++ features) via ball-query idx          (K=67)
// MODE 1: x = relu(bn(prev_raw)) from 64-ch buffer (in-place safe) (K=64)
// MODE 2: x = concat(relu(bn(pool0)), relu(bn(pool1)))             (K=256)
// MODE 3: x = plain read (already-normalized h)                    (K=256)
// POOL  : write per-group (NS) max of raw output instead of full rows.
// Every block writes per-channel (sum, sumsq) partials to P[ch][block].
// ---------------------------------------------------------------------------
template <int COUT, int KTOT, int MODE, int NS, bool POOL, bool BIAS>
__global__ __launch_bounds__(256) void mlp_gemm(
    const float* __restrict__ xin, const float* __restrict__ xin2,
    const float* __restrict__ bnp, const float* __restrict__ bnp2,
    const float* __restrict__ w, const float* __restrict__ bias,
    const int* __restrict__ gidx, const float* __restrict__ xyz,
    const float* __restrict__ nxyz, const float* __restrict__ feats,
    float* __restrict__ out, float* __restrict__ P) {
  constexpr int KC = (KTOT <= 68) ? KTOT : 32;     // K chunk
  constexpr int NCH = (KTOT + KC - 1) / KC;
  constexpr int TC = COUT / 16;                    // cols per thread
  constexpr int XPAD = KC + 1;
  constexpr int XSZ = 64 * XPAD;
  constexpr int EPI = (POOL ? 48 : 32) * COUT;
  constexpr int SM = (XSZ + KC * COUT > EPI) ? (XSZ + KC * COUT) : EPI;
  __shared__ float smem[SM];
  float* xS = smem;
  float* wS = smem + XSZ;

  const int tid = threadIdx.x;
  const int cg = tid & 15, rg = tid >> 4;
  const int row0 = blockIdx.x * 64;
  float acc[4][TC];
#pragma unroll
  for (int i = 0; i < 4; ++i)
#pragma unroll
    for (int t = 0; t < TC; ++t) acc[i][t] = 0.f;

  for (int ch = 0; ch < NCH; ++ch) {
    const int k0 = ch * KC;
    if (ch) __syncthreads();
    // ---- stage x tile [64 rows][KC] (row-major, padded) ----
    for (int e = tid; e < 64 * KC; e += 256) {
      const int r = e / KC, kk = e - r * KC;
      const int kg = k0 + kk;
      const int rowg = row0 + r;
      float v;
      if constexpr (MODE == 0) {
        const int bs = rowg / NS;
        const int p = gidx[rowg];
        const int bb = bs >> 11;
        if (kg < 3)
          v = xyz[(bb * Nn + p) * 3 + kg] - nxyz[bs * 3 + kg];
        else
          v = feats[((bb * Nn + p) << 6) + (kg - 3)];
      } else if constexpr (MODE == 1) {
        v = fmaxf((xin[(size_t)rowg * 64 + kg] - bnp[kg]) * bnp[64 + kg], 0.f);
      } else if constexpr (MODE == 2) {
        if (kg < 128)
          v = fmaxf((xin[(size_t)rowg * 128 + kg] - bnp[kg]) * bnp[128 + kg], 0.f);
        else {
          const int k2 = kg - 128;
          v = fmaxf((xin2[(size_t)rowg * 128 + k2] - bnp2[k2]) * bnp2[128 + k2], 0.f);
        }
      } else {
        v = xin[(size_t)rowg * 256 + kg];
      }
      xS[r * XPAD + kk] = v;
    }
    // ---- stage w chunk [KC][COUT] ----
    for (int e = tid; e < KC * COUT; e += 256) {
      const int kk = e / COUT, c = e - kk * COUT;
      wS[kk * COUT + c] = w[(size_t)(k0 + kk) * COUT + c];
    }
    __syncthreads();
    // ---- FMA loop ----
    for (int kk = 0; kk < KC; ++kk) {
      float xr[4];
#pragma unroll
      for (int i = 0; i < 4; ++i) xr[i] = xS[(rg * 4 + i) * XPAD + kk];
#pragma unroll
      for (int t = 0; t < TC; t += 4) {
        const float4 wv = *(const float4*)&wS[kk * COUT + cg * TC + t];
#pragma unroll
        for (int i = 0; i < 4; ++i) {
          acc[i][t + 0] = fmaf(xr[i], wv.x, acc[i][t + 0]);
          acc[i][t + 1] = fmaf(xr[i], wv.y, acc[i][t + 1]);
          acc[i][t + 2] = fmaf(xr[i], wv.z, acc[i][t + 2]);
          acc[i][t + 3] = fmaf(xr[i], wv.w, acc[i][t + 3]);
        }
      }
    }
  }
  __syncthreads();  // smem reuse below
  if constexpr (BIAS) {
#pragma unroll
    for (int t = 0; t < TC; ++t) {
      const float bv = bias[cg * TC + t];
#pragma unroll
      for (int i = 0; i < 4; ++i) acc[i][t] += bv;
    }
  }
  // ---- per-block BN partials (+ group max for POOL) ----
  float* ssum = smem;
  float* ssq = smem + 16 * COUT;
  float* pbuf = smem + 32 * COUT;
  const int colb = cg * TC;
#pragma unroll
  for (int t = 0; t < TC; ++t) {
    float s = 0.f, q = 0.f, m = -3.4e38f;
#pragma unroll
    for (int i = 0; i < 4; ++i) {
      const float v = acc[i][t];
      s += v;
      q = fmaf(v, v, q);
      m = fmaxf(m, v);
    }
    ssum[rg * COUT + colb + t] = s;
    ssq[rg * COUT + colb + t] = q;
    if constexpr (POOL) pbuf[rg * COUT + colb + t] = m;
  }
  __syncthreads();
  const int gX = gridDim.x;
  for (int c = tid; c < COUT; c += 256) {
    float s = 0.f, q = 0.f;
#pragma unroll
    for (int rr = 0; rr < 16; ++rr) {
      s += ssum[rr * COUT + c];
      q += ssq[rr * COUT + c];
    }
    P[(size_t)c * gX + blockIdx.x] = s;
    P[(size_t)(COUT + c) * gX + blockIdx.x] = q;
  }
  if constexpr (POOL) {
    constexpr int G = 64 / NS, RPG = NS / 4;
    for (int o = tid; o < G * COUT; o += 256) {
      const int g = o / COUT, c = o - g * COUT;
      float m = pbuf[(g * RPG) * COUT + c];
#pragma unroll
      for (int qq = 1; qq < RPG; ++qq) m = fmaxf(m, pbuf[(g * RPG + qq) * COUT + c]);
      out[(size_t)(blockIdx.x * G + g) * COUT + c] = m;
    }
  } else {
#pragma unroll
    for (int i = 0; i < 4; ++i) {
      float* op = out + (size_t)(row0 + rg * 4 + i) * COUT + colb;
#pragma unroll
      for (int t = 0; t < TC; t += 4) {
        *(float4*)(op + t) = make_float4(acc[i][t], acc[i][t + 1], acc[i][t + 2], acc[i][t + 3]);
      }
    }
  }
}

// ---------------------------------------------------------------------------
// BN finalize: one block per channel, coalesced partial reads, deterministic
// f64 LDS tree reduction -> mu, rstd. bnp layout: [mu(C), rstd(C)].
// ---------------------------------------------------------------------------
__global__ __launch_bounds__(256) void bn_finalize(const float* __restrict__ P, int gX,
                                                   int M, int C, float* __restrict__ bnp) {
  __shared__ double sh[512];
  const int c = blockIdx.x;
  const int tid = threadIdx.x;
  const float* psum = P + (size_t)c * gX;
  const float* psq = P + (size_t)(C + c) * gX;
  double s = 0, q = 0;
  for (int i = tid; i < gX; i += 256) {
    s += (double)psum[i];
    q += (double)psq[i];
  }
  sh[tid] = s;
  sh[256 + tid] = q;
  __syncthreads();
  for (int off = 128; off; off >>= 1) {
    if (tid < off) {
      sh[tid] += sh[tid + off];
      sh[256 + tid] += sh[256 + tid + off];
    }
    __syncthreads();
  }
  if (tid == 0) {
    const double invM = 1.0 / (double)M;
    const double mu = sh[0] * invM;
    const double var = sh[256] * invM - mu * mu;
    bnp[c] = (float)mu;
    bnp[C + c] = (float)(1.0 / sqrt(var + 1e-5));
  }
}

// h = relu(bn(agg_raw)) -> d_out (also consumed by conf layer)
__global__ __launch_bounds__(256) void h_store_kernel(const float* __restrict__ agg,
                                                      const float* __restrict__ bnp,
                                                      float* __restrict__ hout) {
  const int t = blockIdx.x * 256 + threadIdx.x;
  const int c = t & 255;
  const float v = (agg[t] - bnp[c]) * bnp[256 + c];
  hout[t] = fmaxf(v, 0.f);
}

// cls = relu(bn(conf_raw)) @ cls_w + cls_b   (one wave per row)
__global__ __launch_bounds__(256) void cls_kernel(const float* __restrict__ craw,
                                                  const float* __restrict__ bnp,
                                                  const float* __restrict__ clsw,
                                                  const float* __restrict__ clsb,
                                                  float* __restrict__ outc) {
  const int wid = threadIdx.x >> 6, lane = threadIdx.x & 63;
  const int row = blockIdx.x * 4 + wid;
  const float* cr = craw + (size_t)row * 256;
  float a0 = 0.f, a1 = 0.f, a2 = 0.f;
#pragma unroll 4
  for (int k = lane; k < 256; k += 64) {
    float x = fmaxf((cr[k] - bnp[k]) * bnp[256 + k], 0.f);
    a0 = fmaf(x, clsw[k * 3 + 0], a0);
    a1 = fmaf(x, clsw[k * 3 + 1], a1);
    a2 = fmaf(x, clsw[k * 3 + 2], a2);
  }
#pragma unroll
  for (int off = 32; off; off >>= 1) {
    a0 += __shfl_down(a0, off);
    a1 += __shfl_down(a1, off);
    a2 += __shfl_down(a2, off);
  }
  if (lane == 0) {
    outc[row * 3 + 0] = a0 + clsb[0];
    outc[row * 3 + 1] = a1 + clsb[1];
    outc[row * 3 + 2] = a2 + clsb[2];
  }
}

// ---------------------------------------------------------------------------
extern "C" void kernel_launch(void* const* d_in, const int* in_sizes, int n_in,
                              void* d_out, int out_size, void* d_ws, size_t ws_size,
                              hipStream_t stream) {
  (void)in_sizes; (void)n_in; (void)out_size; (void)ws_size;
  const float* xyz = (const float*)d_in[0];
  const float* feats = (const float*)d_in[1];
  const float* w00 = (const float*)d_in[2];
  const float* w01 = (const float*)d_in[3];
  const float* w02 = (const float*)d_in[4];
  const float* w10 = (const float*)d_in[5];
  const float* w11 = (const float*)d_in[6];
  const float* w12 = (const float*)d_in[7];
  const float* aggw = (const float*)d_in[8];
  const float* aggb = (const float*)d_in[9];
  const float* confw = (const float*)d_in[10];
  const float* clsw = (const float*)d_in[11];
  const float* clsb = (const float*)d_in[12];

  float* outp = (float*)d_out;
  float* nxyz = outp;                               // [BS,3]
  float* hout = outp + (size_t)BS * 3;              // [BS,256]
  float* clsout = hout + (size_t)BS * 256;          // [BS,3]

  char* ws = (char*)d_ws;
  const size_t MB = 1u << 20;
  int* idx0 = (int*)(ws + 0);                       // 1 MB
  int* idx1 = (int*)(ws + 1 * MB);                  // 2 MB
  float* bnb = (float*)(ws + 3 * MB);               // bn params (2048 floats)
  float* P = (float*)(ws + 4 * MB);                 // partials, up to 8 MB
  float* pool0 = (float*)(ws + 12 * MB);            // [BS,128]
  float* pool1 = (float*)(ws + 20 * MB);            // [BS,128]
  float* aggraw = (float*)(ws + 28 * MB);           // [BS,256]
  float* confraw = (float*)(ws + 44 * MB);          // [BS,256]
  float* hA = (float*)(ws + 60 * MB);               // [524288,64] (layers 1/2 in-place)

  fps_kernel<<<Bb, 1024, 0, stream>>>(xyz, nxyz);
  ballq_kernel<<<BS / 4, 256, 0, stream>>>(xyz, nxyz, idx0, idx1);

  // ---- scale 0 (r=0.4, ns=16), M = 262144 ----
  mlp_gemm<64, 67, 0, 16, false, false><<<4096, 256, 0, stream>>>(
      nullptr, nullptr, nullptr, nullptr, w00, nullptr, idx0, xyz, nxyz, feats, hA, P);
  bn_finalize<<<64, 256, 0, stream>>>(P, 4096, 262144, 64, bnb + 0);
  mlp_gemm<64, 64, 1, 1, false, false><<<4096, 256, 0, stream>>>(
      hA, nullptr, bnb + 0, nullptr, w01, nullptr, nullptr, nullptr, nullptr, nullptr, hA, P);
  bn_finalize<<<64, 256, 0, stream>>>(P, 4096, 262144, 64, bnb + 128);
  mlp_gemm<128, 64, 1, 16, true, false><<<4096, 256, 0, stream>>>(
      hA, nullptr, bnb + 128, nullptr, w02, nullptr, nullptr, nullptr, nullptr, nullptr, pool0, P);
  bn_finalize<<<128, 256, 0, stream>>>(P, 4096, 262144, 128, bnb + 256);

  // ---- scale 1 (r=0.8, ns=32), M = 524288 ----
  mlp_gemm<64, 67, 0, 32, false, false><<<8192, 256, 0, stream>>>(
      nullptr, nullptr, nullptr, nullptr, w10, nullptr, idx1, xyz, nxyz, feats, hA, P);
  bn_finalize<<<64, 256, 0, stream>>>(P, 8192, 524288, 64, bnb + 512);
  mlp_gemm<64, 64, 1, 1, false, false><<<8192, 256, 0, stream>>>(
      hA, nullptr, bnb + 512, nullptr, w11, nullptr, nullptr, nullptr, nullptr, nullptr, hA, P);
  bn_finalize<<<64, 256, 0, stream>>>(P, 8192, 524288, 64, bnb + 640);
  mlp_gemm<128, 64, 1, 32, true, false><<<8192, 256, 0, stream>>>(
      hA, nullptr, bnb + 640, nullptr, w12, nullptr, nullptr, nullptr, nullptr, nullptr, pool1, P);
  bn_finalize<<<128, 256, 0, stream>>>(P, 8192, 524288, 128, bnb + 768);

  // ---- aggregation: concat(bn3_0(pool0), bn3_1(pool1)) @ agg_w + agg_b ----
  mlp_gemm<256, 256, 2, 1, false, true><<<256, 256, 0, stream>>>(
      pool0, pool1, bnb + 256, bnb + 768, aggw, aggb, nullptr, nullptr, nullptr, nullptr, aggraw, P);
  bn_finalize<<<256, 256, 0, stream>>>(P, 256, 16384, 256, bnb + 1024);
  h_store_kernel<<<BS, 256, 0, stream>>>(aggraw, bnb + 1024, hout);

  // ---- confidence hidden layer ----
  mlp_gemm<256, 256, 3, 1, false, false><<<256, 256, 0, stream>>>(
      hout, nullptr, nullptr, nullptr, confw, nullptr, nullptr, nullptr, nullptr, nullptr, confraw, P);
  bn_finalize<<<256, 256, 0, stream>>>(P, 256, 16384, 256, bnb + 1536);

  // ---- classifier ----
  cls_kernel<<<BS / 4, 256, 0, stream>>>(confraw, bnb + 1536, clsw, clsb, clsout);
}

// Round 5
// 3830.196 us; speedup vs baseline: 1.7212x; 1.2829x over previous
//
#include <hip/hip_runtime.h>
#include <cstdint>
#include <cstddef>

// Problem constants (fixed by reference setup_inputs)
constexpr int Bb = 8;
constexpr int Nn = 8192;
constexpr int Ss = 2048;
constexpr int BS = Bb * Ss;  // 16384

typedef float vfloat2 __attribute__((ext_vector_type(2)));

// ---------------------------------------------------------------------------
// FPS: one block per batch, 1024 threads, 8 points/thread (no spill; the
// 32-pts/thread variant spilled and regressed — round 3).
// dist[] updates stay exact f64 (bit-matches np reference — verified r1-r4).
// Round-5 deltas (decisions provably identical):
//  - packed-f32 (float2 -> v_pk_*) screening, certified upper-bound skip
//  - value-only f32 wave max + uniqueness ballot; f64 argmax fallback only on
//    f32 collision (monotone rounding: unique f32 max IS the f64 argmax)
//  - f32 block reduce with the same certified fallback (scan tied entries f64)
//  - LDS index log, single final gather (no global store in the loop)
// ---------------------------------------------------------------------------
__global__ __launch_bounds__(1024) void fps_kernel(const float* __restrict__ xyz,
                                                   float* __restrict__ new_xyz) {
  __shared__ float lx[Nn * 3];             // 96 KB: batch point cloud
  __shared__ int sidx[Ss];                 // 8 KB: selected-index log
  __shared__ float rv32[2][16];
  __shared__ double rv64[2][16];
  __shared__ int ri[2][16];
  const int b = blockIdx.x;
  const int tid = threadIdx.x;
  const float* xb = xyz + (size_t)b * Nn * 3;
  for (int e = tid; e < Nn * 3; e += 1024) lx[e] = xb[e];
  __syncthreads();
  vfloat2 px2[4], py2[4], pz2[4], df2[4];
  double dist[8];
#pragma unroll
  for (int jj = 0; jj < 4; ++jj) {
    const int p0 = tid + (2 * jj) * 1024, p1 = tid + (2 * jj + 1) * 1024;
    px2[jj] = (vfloat2){lx[p0 * 3 + 0], lx[p1 * 3 + 0]};
    py2[jj] = (vfloat2){lx[p0 * 3 + 1], lx[p1 * 3 + 1]};
    pz2[jj] = (vfloat2){lx[p0 * 3 + 2], lx[p1 * 3 + 2]};
    df2[jj] = (vfloat2){3.0e38f, 3.0e38f};   // force exact path on first touch
    dist[2 * jj] = 1e10;
    dist[2 * jj + 1] = 1e10;
  }
  const int lane = tid & 63, wid = tid >> 6;
  int cur = 0;
  double lv = -1.0;                        // per-lane cached local argmax
  int li = tid;
  float wv32_c = -1.0f;                    // cached wave argmax (all lanes)
  double wv64_c = -1.0;
  int wi_c = 0;
  for (int i = 0; i < Ss; ++i) {
    if (tid == 0) sidx[i] = cur;           // LDS log (visible after barrier)
    const float cxf = lx[cur * 3 + 0], cyf = lx[cur * 3 + 1], czf = lx[cur * 3 + 2];
    const vfloat2 cx2 = {cxf, cxf}, cy2 = {cyf, cyf}, cz2 = {czf, czf};
    // ---- packed-f32 screening: which j might update? ----
    unsigned need = 0;
#pragma unroll
    for (int jj = 0; jj < 4; ++jj) {
      const vfloat2 dx = px2[jj] - cx2;
      const vfloat2 dy = py2[jj] - cy2;
      const vfloat2 dz = pz2[jj] - cz2;
      const vfloat2 d2 = dx * dx + dy * dy + dz * dz;
      need |= (d2.x <= df2[jj].x) ? (1u << (2 * jj)) : 0u;
      need |= (d2.y <= df2[jj].y) ? (1u << (2 * jj + 1)) : 0u;
    }
    bool changed = false;
    if (need) {                            // rare path: exact f64 updates
#pragma unroll
      for (int j = 0; j < 8; ++j) {
        if (need & (1u << j)) {
          const float pxs = px2[j >> 1][j & 1];
          const float pys = py2[j >> 1][j & 1];
          const float pzs = pz2[j >> 1][j & 1];
          double dx = __dsub_rn((double)pxs, (double)cxf);
          double dy = __dsub_rn((double)pys, (double)cyf);
          double dz = __dsub_rn((double)pzs, (double)czf);
          double d = __dadd_rn(__dadd_rn(__dmul_rn(dx, dx), __dmul_rn(dy, dy)),
                               __dmul_rn(dz, dz));
          if (d < dist[j]) {
            dist[j] = d;
            const float dfn = (float)d * 1.000002f;  // certified upper bound
            if (j & 1) df2[j >> 1].y = dfn; else df2[j >> 1].x = dfn;
            changed = true;
          }
        }
      }
    }
    const unsigned long long anyb = __ballot(changed);
    if (changed) {                         // rescan local max only when needed
      lv = -1.0;
      li = 0;
#pragma unroll
      for (int j = 0; j < 8; ++j) {
        if (dist[j] > lv) { lv = dist[j]; li = tid + j * 1024; }  // j asc => smallest idx on tie
      }
    }
    if (anyb) {                            // wave argmax only if wave changed
      const float lv32 = (float)lv;
      float m32 = lv32;
#pragma unroll
      for (int off = 1; off < 64; off <<= 1) m32 = fmaxf(m32, __shfl_xor(m32, off));
      const unsigned long long em = __ballot(lv32 == m32);
      if (__popcll(em) == 1) {             // unique f32 max == f64 argmax
        const int w = (int)__builtin_ctzll(em);
        wi_c = __shfl(li, w);
        wv64_c = __shfl(lv, w);
        wv32_c = m32;
      } else {                             // rare: f64 argmax w/ idx tie-break
        double bv = lv;
        int bi = li;
#pragma unroll
        for (int off = 1; off < 64; off <<= 1) {
          double ov = __shfl_xor(bv, off);
          int oi = __shfl_xor(bi, off);
          if (ov > bv || (ov == bv && oi < bi)) { bv = ov; bi = oi; }
        }
        wv64_c = bv;
        wi_c = bi;
        wv32_c = (float)bv;
      }
    }
    const int pb = i & 1;
    if (lane == 0) { rv32[pb][wid] = wv32_c; rv64[pb][wid] = wv64_c; ri[pb][wid] = wi_c; }
    __syncthreads();
    // ---- block reduce: f32 value max over 16 entries, unique-winner path ----
    const float mine = rv32[pb][lane & 15];
    float g32 = mine;
#pragma unroll
    for (int off = 1; off < 16; off <<= 1) g32 = fmaxf(g32, __shfl_xor(g32, off));
    const unsigned long long bm = __ballot((lane < 16) && (mine == g32));
    if (__popcll(bm) == 1) {
      cur = ri[pb][(int)__builtin_ctzll(bm)];
    } else {                               // rare: f64 among f32-tied entries
      double gv = -1.0;
      int gi = 0x7fffffff;
      unsigned mm = (unsigned)bm;
      while (mm) {
        const int w = (int)__builtin_ctz(mm);
        mm &= mm - 1;
        const double ov = rv64[pb][w];
        const int oi = ri[pb][w];
        if (ov > gv || (ov == gv && oi < gi)) { gv = ov; gi = oi; }
      }
      cur = gi;
    }
  }
  __syncthreads();
  // final gather: new_xyz[i][c] = lx[sidx[i]*3 + c]
  float* nxb = new_xyz + (size_t)b * Ss * 3;
  for (int e = tid; e < Ss * 3; e += 1024) {
    const int i = e / 3, c = e - i * 3;
    nxb[e] = lx[sidx[i] * 3 + c];
  }
}

// ---------------------------------------------------------------------------
// Ball query, both scales fused. One wave per center. f64 distance compare
// (bit-matches np). First nsample in-range points in original order; pad with
// first hit (0 if none).
// ---------------------------------------------------------------------------
__global__ __launch_bounds__(256) void ballq_kernel(const float* __restrict__ xyz,
                                                    const float* __restrict__ nxyz,
                                                    int* __restrict__ idx0,
                                                    int* __restrict__ idx1) {
  const int wid = threadIdx.x >> 6, lane = threadIdx.x & 63;
  const int bs = blockIdx.x * 4 + wid;
  const int b = bs >> 11;  // S = 2048
  const float* xb = xyz + (size_t)b * Nn * 3;
  const double cx = (double)nxyz[bs * 3 + 0];
  const double cy = (double)nxyz[bs * 3 + 1];
  const double cz = (double)nxyz[bs * 3 + 2];
  const double R0 = 0.4 * 0.4, R1 = 0.8 * 0.8;
  int cnt0 = 0, cnt1 = 0, first0 = 0, first1 = 0;
  const unsigned long long lmask = (1ull << lane) - 1ull;
  for (int base = 0; base < Nn; base += 64) {
    const int p = base + lane;
    double dx = __dsub_rn((double)xb[p * 3 + 0], cx);
    double dy = __dsub_rn((double)xb[p * 3 + 1], cy);
    double dz = __dsub_rn((double)xb[p * 3 + 2], cz);
    double d2 = __dadd_rn(__dadd_rn(__dmul_rn(dx, dx), __dmul_rn(dy, dy)), __dmul_rn(dz, dz));
    const bool in0 = d2 < R0, in1 = d2 < R1;
    unsigned long long m0 = __ballot(in0);
    unsigned long long m1 = __ballot(in1);
    if (cnt0 < 16 && m0) {
      if (cnt0 == 0) first0 = base + __builtin_ctzll(m0);
      int r = (int)__popcll(m0 & lmask);
      if (in0 && cnt0 + r < 16) idx0[bs * 16 + cnt0 + r] = p;
      cnt0 += (int)__popcll(m0);
    }
    if (cnt1 < 32 && m1) {
      if (cnt1 == 0) first1 = base + __builtin_ctzll(m1);
      int r = (int)__popcll(m1 & lmask);
      if (in1 && cnt1 + r < 32) idx1[bs * 32 + cnt1 + r] = p;
      cnt1 += (int)__popcll(m1);
    }
    if (cnt0 >= 16 && cnt1 >= 32) break;
  }
  const int f0 = cnt0 < 16 ? cnt0 : 16;
  for (int j = f0 + lane; j < 16; j += 64) idx0[bs * 16 + j] = first0;
  const int f1 = cnt1 < 32 ? cnt1 : 32;
  for (int j = f1 + lane; j < 32; j += 64) idx1[bs * 32 + j] = first1;
}

// ---------------------------------------------------------------------------
// Generic tall-skinny GEMM with fused input transforms and BN-stat partials.
// Tile: 64 rows x COUT cols, 256 threads, per-thread 4 rows x (COUT/16) cols.
// MODE 0: gather (rel-xyz ++ features) via ball-query idx          (K=67)
// MODE 1: x = relu(bn(prev_raw)) from 64-ch buffer (in-place safe) (K=64)
// MODE 2: x = concat(relu(bn(pool0)), relu(bn(pool1)))             (K=256)
// MODE 3: x = plain read (already-normalized h)                    (K=256)
// POOL  : write per-group (NS) max of raw output instead of full rows.
// Every block writes per-channel (sum, sumsq) partials to P[ch][block].
// ---------------------------------------------------------------------------
template <int COUT, int KTOT, int MODE, int NS, bool POOL, bool BIAS>
__global__ __launch_bounds__(256) void mlp_gemm(
    const float* __restrict__ xin, const float* __restrict__ xin2,
    const float* __restrict__ bnp, const float* __restrict__ bnp2,
    const float* __restrict__ w, const float* __restrict__ bias,
    const int* __restrict__ gidx, const float* __restrict__ xyz,
    const float* __restrict__ nxyz, const float* __restrict__ feats,
    float* __restrict__ out, float* __restrict__ P) {
  constexpr int KC = (KTOT <= 68) ? KTOT : 32;     // K chunk
  constexpr int NCH = (KTOT + KC - 1) / KC;
  constexpr int TC = COUT / 16;                    // cols per thread
  constexpr int XPAD = KC + 1;
  constexpr int XSZ = 64 * XPAD;
  constexpr int EPI = (POOL ? 48 : 32) * COUT;
  constexpr int SM = (XSZ + KC * COUT > EPI) ? (XSZ + KC * COUT) : EPI;
  __shared__ float smem[SM];
  float* xS = smem;
  float* wS = smem + XSZ;

  const int tid = threadIdx.x;
  const int cg = tid & 15, rg = tid >> 4;
  const int row0 = blockIdx.x * 64;
  float acc[4][TC];
#pragma unroll
  for (int i = 0; i < 4; ++i)
#pragma unroll
    for (int t = 0; t < TC; ++t) acc[i][t] = 0.f;

  for (int ch = 0; ch < NCH; ++ch) {
    const int k0 = ch * KC;
    if (ch) __syncthreads();
    // ---- stage x tile [64 rows][KC] (row-major, padded) ----
    for (int e = tid; e < 64 * KC; e += 256) {
      const int r = e / KC, kk = e - r * KC;
      const int kg = k0 + kk;
      const int rowg = row0 + r;
      float v;
      if constexpr (MODE == 0) {
        const int bs = rowg / NS;
        const int p = gidx[rowg];
        const int bb = bs >> 11;
        if (kg < 3)
          v = xyz[(bb * Nn + p) * 3 + kg] - nxyz[bs * 3 + kg];
        else
          v = feats[((bb * Nn + p) << 6) + (kg - 3)];
      } else if constexpr (MODE == 1) {
        v = fmaxf((xin[(size_t)rowg * 64 + kg] - bnp[kg]) * bnp[64 + kg], 0.f);
      } else if constexpr (MODE == 2) {
        if (kg < 128)
          v = fmaxf((xin[(size_t)rowg * 128 + kg] - bnp[kg]) * bnp[128 + kg], 0.f);
        else {
          const int k2 = kg - 128;
          v = fmaxf((xin2[(size_t)rowg * 128 + k2] - bnp2[k2]) * bnp2[128 + k2], 0.f);
        }
      } else {
        v = xin[(size_t)rowg * 256 + kg];
      }
      xS[r * XPAD + kk] = v;
    }
    // ---- stage w chunk [KC][COUT] ----
    for (int e = tid; e < KC * COUT; e += 256) {
      const int kk = e / COUT, c = e - kk * COUT;
      wS[kk * COUT + c] = w[(size_t)(k0 + kk) * COUT + c];
    }
    __syncthreads();
    // ---- FMA loop ----
    for (int kk = 0; kk < KC; ++kk) {
      float xr[4];
#pragma unroll
      for (int i = 0; i < 4; ++i) xr[i] = xS[(rg * 4 + i) * XPAD + kk];
#pragma unroll
      for (int t = 0; t < TC; t += 4) {
        const float4 wv = *(const float4*)&wS[kk * COUT + cg * TC + t];
#pragma unroll
        for (int i = 0; i < 4; ++i) {
          acc[i][t + 0] = fmaf(xr[i], wv.x, acc[i][t + 0]);
          acc[i][t + 1] = fmaf(xr[i], wv.y, acc[i][t + 1]);
          acc[i][t + 2] = fmaf(xr[i], wv.z, acc[i][t + 2]);
          acc[i][t + 3] = fmaf(xr[i], wv.w, acc[i][t + 3]);
        }
      }
    }
  }
  __syncthreads();  // smem reuse below
  if constexpr (BIAS) {
#pragma unroll
    for (int t = 0; t < TC; ++t) {
      const float bv = bias[cg * TC + t];
#pragma unroll
      for (int i = 0; i < 4; ++i) acc[i][t] += bv;
    }
  }
  // ---- per-block BN partials (+ group max for POOL) ----
  float* ssum = smem;
  float* ssq = smem + 16 * COUT;
  float* pbuf = smem + 32 * COUT;
  const int colb = cg * TC;
#pragma unroll
  for (int t = 0; t < TC; ++t) {
    float s = 0.f, q = 0.f, m = -3.4e38f;
#pragma unroll
    for (int i = 0; i < 4; ++i) {
      const float v = acc[i][t];
      s += v;
      q = fmaf(v, v, q);
      m = fmaxf(m, v);
    }
    ssum[rg * COUT + colb + t] = s;
    ssq[rg * COUT + colb + t] = q;
    if constexpr (POOL) pbuf[rg * COUT + colb + t] = m;
  }
  __syncthreads();
  const int gX = gridDim.x;
  for (int c = tid; c < COUT; c += 256) {
    float s = 0.f, q = 0.f;
#pragma unroll
    for (int rr = 0; rr < 16; ++rr) {
      s += ssum[rr * COUT + c];
      q += ssq[rr * COUT + c];
    }
    P[(size_t)c * gX + blockIdx.x] = s;
    P[(size_t)(COUT + c) * gX + blockIdx.x] = q;
  }
  if constexpr (POOL) {
    constexpr int G = 64 / NS, RPG = NS / 4;
    for (int o = tid; o < G * COUT; o += 256) {
      const int g = o / COUT, c = o - g * COUT;
      float m = pbuf[(g * RPG) * COUT + c];
#pragma unroll
      for (int qq = 1; qq < RPG; ++qq) m = fmaxf(m, pbuf[(g * RPG + qq) * COUT + c]);
      out[(size_t)(blockIdx.x * G + g) * COUT + c] = m;
    }
  } else {
#pragma unroll
    for (int i = 0; i < 4; ++i) {
      float* op = out + (size_t)(row0 + rg * 4 + i) * COUT + colb;
#pragma unroll
      for (int t = 0; t < TC; t += 4) {
        *(float4*)(op + t) = make_float4(acc[i][t], acc[i][t + 1], acc[i][t + 2], acc[i][t + 3]);
      }
    }
  }
}

// ---------------------------------------------------------------------------
// BN finalize: one block per channel, coalesced partial reads, deterministic
// f64 LDS tree reduction -> mu, rstd. bnp layout: [mu(C), rstd(C)].
// ---------------------------------------------------------------------------
__global__ __launch_bounds__(256) void bn_finalize(const float* __restrict__ P, int gX,
                                                   int M, int C, float* __restrict__ bnp) {
  __shared__ double sh[512];
  const int c = blockIdx.x;
  const int tid = threadIdx.x;
  const float* psum = P + (size_t)c * gX;
  const float* psq = P + (size_t)(C + c) * gX;
  double s = 0, q = 0;
  for (int i = tid; i < gX; i += 256) {
    s += (double)psum[i];
    q += (double)psq[i];
  }
  sh[tid] = s;
  sh[256 + tid] = q;
  __syncthreads();
  for (int off = 128; off; off >>= 1) {
    if (tid < off) {
      sh[tid] += sh[tid + off];
      sh[256 + tid] += sh[256 + tid + off];
    }
    __syncthreads();
  }
  if (tid == 0) {
    const double invM = 1.0 / (double)M;
    const double mu = sh[0] * invM;
    const double var = sh[256] * invM - mu * mu;
    bnp[c] = (float)mu;
    bnp[C + c] = (float)(1.0 / sqrt(var + 1e-5));
  }
}

// h = relu(bn(agg_raw)) -> d_out (also consumed by conf layer)
__global__ __launch_bounds__(256) void h_store_kernel(const float* __restrict__ agg,
                                                      const float* __restrict__ bnp,
                                                      float* __restrict__ hout) {
  const int t = blockIdx.x * 256 + threadIdx.x;
  const int c = t & 255;
  const float v = (agg[t] - bnp[c]) * bnp[256 + c];
  hout[t] = fmaxf(v, 0.f);
}

// cls = relu(bn(conf_raw)) @ cls_w + cls_b   (one wave per row)
__global__ __launch_bounds__(256) void cls_kernel(const float* __restrict__ craw,
                                                  const float* __restrict__ bnp,
                                                  const float* __restrict__ clsw,
                                                  const float* __restrict__ clsb,
                                                  float* __restrict__ outc) {
  const int wid = threadIdx.x >> 6, lane = threadIdx.x & 63;
  const int row = blockIdx.x * 4 + wid;
  const float* cr = craw + (size_t)row * 256;
  float a0 = 0.f, a1 = 0.f, a2 = 0.f;
#pragma unroll 4
  for (int k = lane; k < 256; k += 64) {
    float x = fmaxf((cr[k] - bnp[k]) * bnp[256 + k], 0.f);
    a0 = fmaf(x, clsw[k * 3 + 0], a0);
    a1 = fmaf(x, clsw[k * 3 + 1], a1);
    a2 = fmaf(x, clsw[k * 3 + 2], a2);
  }
#pragma unroll
  for (int off = 32; off; off >>= 1) {
    a0 += __shfl_down(a0, off);
    a1 += __shfl_down(a1, off);
    a2 += __shfl_down(a2, off);
  }
  if (lane == 0) {
    outc[row * 3 + 0] = a0 + clsb[0];
    outc[row * 3 + 1] = a1 + clsb[1];
    outc[row * 3 + 2] = a2 + clsb[2];
  }
}

// ---------------------------------------------------------------------------
extern "C" void kernel_launch(void* const* d_in, const int* in_sizes, int n_in,
                              void* d_out, int out_size, void* d_ws, size_t ws_size,
                              hipStream_t stream) {
  (void)in_sizes; (void)n_in; (void)out_size; (void)ws_size;
  const float* xyz = (const float*)d_in[0];
  const float* feats = (const float*)d_in[1];
  const float* w00 = (const float*)d_in[2];
  const float* w01 = (const float*)d_in[3];
  const float* w02 = (const float*)d_in[4];
  const float* w10 = (const float*)d_in[5];
  const float* w11 = (const float*)d_in[6];
  const float* w12 = (const float*)d_in[7];
  const float* aggw = (const float*)d_in[8];
  const float* aggb = (const float*)d_in[9];
  const float* confw = (const float*)d_in[10];
  const float* clsw = (const float*)d_in[11];
  const float* clsb = (const float*)d_in[12];

  float* outp = (float*)d_out;
  float* nxyz = outp;                               // [BS,3]
  float* hout = outp + (size_t)BS * 3;              // [BS,256]
  float* clsout = hout + (size_t)BS * 256;          // [BS,3]

  char* ws = (char*)d_ws;
  const size_t MB = 1u << 20;
  int* idx0 = (int*)(ws + 0);                       // 1 MB
  int* idx1 = (int*)(ws + 1 * MB);                  // 2 MB
  float* bnb = (float*)(ws + 3 * MB);               // bn params (2048 floats)
  float* P = (float*)(ws + 4 * MB);                 // partials, up to 8 MB
  float* pool0 = (float*)(ws + 12 * MB);            // [BS,128]
  float* pool1 = (float*)(ws + 20 * MB);            // [BS,128]
  float* aggraw = (float*)(ws + 28 * MB);           // [BS,256]
  float* confraw = (float*)(ws + 44 * MB);          // [BS,256]
  float* hA = (float*)(ws + 60 * MB);               // [524288,64] (layers 1/2 in-place)

  fps_kernel<<<Bb, 1024, 0, stream>>>(xyz, nxyz);
  ballq_kernel<<<BS / 4, 256, 0, stream>>>(xyz, nxyz, idx0, idx1);

  // ---- scale 0 (r=0.4, ns=16), M = 262144 ----
  mlp_gemm<64, 67, 0, 16, false, false><<<4096, 256, 0, stream>>>(
      nullptr, nullptr, nullptr, nullptr, w00, nullptr, idx0, xyz, nxyz, feats, hA, P);
  bn_finalize<<<64, 256, 0, stream>>>(P, 4096, 262144, 64, bnb + 0);
  mlp_gemm<64, 64, 1, 1, false, false><<<4096, 256, 0, stream>>>(
      hA, nullptr, bnb + 0, nullptr, w01, nullptr, nullptr, nullptr, nullptr, nullptr, hA, P);
  bn_finalize<<<64, 256, 0, stream>>>(P, 4096, 262144, 64, bnb + 128);
  mlp_gemm<128, 64, 1, 16, true, false><<<4096, 256, 0, stream>>>(
      hA, nullptr, bnb + 128, nullptr, w02, nullptr, nullptr, nullptr, nullptr, nullptr, pool0, P);
  bn_finalize<<<128, 256, 0, stream>>>(P, 4096, 262144, 128, bnb + 256);

  // ---- scale 1 (r=0.8, ns=32), M = 524288 ----
  mlp_gemm<64, 67, 0, 32, false, false><<<8192, 256, 0, stream>>>(
      nullptr, nullptr, nullptr, nullptr, w10, nullptr, idx1, xyz, nxyz, feats, hA, P);
  bn_finalize<<<64, 256, 0, stream>>>(P, 8192, 524288, 64, bnb + 512);
  mlp_gemm<64, 64, 1, 1, false, false><<<8192, 256, 0, stream>>>(
      hA, nullptr, bnb + 512, nullptr, w11, nullptr, nullptr, nullptr, nullptr, nullptr, hA, P);
  bn_finalize<<<64, 256, 0, stream>>>(P, 8192, 524288, 64, bnb + 640);
  mlp_gemm<128, 64, 1, 32, true, false><<<8192, 256, 0, stream>>>(
      hA, nullptr, bnb + 640, nullptr, w12, nullptr, nullptr, nullptr, nullptr, nullptr, pool1, P);
  bn_finalize<<<128, 256, 0, stream>>>(P, 8192, 524288, 128, bnb + 768);

  // ---- aggregation: concat(bn3_0(pool0), bn3_1(pool1)) @ agg_w + agg_b ----
  mlp_gemm<256, 256, 2, 1, false, true><<<256, 256, 0, stream>>>(
      pool0, pool1, bnb + 256, bnb + 768, aggw, aggb, nullptr, nullptr, nullptr, nullptr, aggraw, P);
  bn_finalize<<<256, 256, 0, stream>>>(P, 256, 16384, 256, bnb + 1024);
  h_store_kernel<<<BS, 256, 0, stream>>>(aggraw, bnb + 1024, hout);

  // ---- confidence hidden layer ----
  mlp_gemm<256, 256, 3, 1, false, false><<<256, 256, 0, stream>>>(
      hout, nullptr, nullptr, nullptr, confw, nullptr, nullptr, nullptr, nullptr, nullptr, confraw, P);
  bn_finalize<<<256, 256, 0, stream>>>(P, 256, 16384, 256, bnb + 1536);

  // ---- classifier ----
  cls_kernel<<<BS / 4, 256, 0, stream>>>(confraw, bnb + 1536, clsw, clsb, clsout);
}